// Round 1
// baseline (843.642 us; speedup 1.0000x reference)
//
#include <hip/hip_runtime.h>
#include <hip/hip_bf16.h>

#define DTF (1.0f/120.0f)

constexpr int Bn = 2048;
constexpr int Tn = 2048;
constexpr int NS = Tn - 1;      // 2047 scan steps
constexpr int ROWF = 28;        // floats per table row (18 K + 6 Sinv + det + pad)

// d_ws layout:
//   [0..7]   double accumulator
//   [8..11]  int t_stop
//   [16..)   table: NS rows * 28 floats (112 B each, 16B-aligned)

__device__ __forceinline__ float sgnf(float x) { return (float)((x > 0.f) - (x < 0.f)); }

__global__ void riccati_kernel(const float* __restrict__ params, char* __restrict__ ws)
{
    if (threadIdx.x != 0 || blockIdx.x != 0) return;
    double* accp = (double*)ws;
    *accp = 0.0;                       // zero the global accumulator every launch
    int* tstop = (int*)(ws + 8);
    float* tab = (float*)(ws + 16);

    const float dt = DTF;
    const float damping = params[1];
    const float a = 1.f - dt * damping;
    const float R0 = 2.5e-7f, R1 = 2.5e-7f, R2 = 9.1e-3f;
    const float Qd[6] = {2e-10f, 2e-10f, 3e-7f, 3e-7f, 1e-2f, 1e-1f};

    float P[6][6];
    for (int i = 0; i < 6; i++)
        for (int j = 0; j < 6; j++) P[i][j] = (i == j) ? 0.01f : 0.f;

    int stop = NS - 1;
    for (int t = 0; t < NS; ++t) {
        float A_[6][6], Pp[6][6];
        // A = F * P   (F sparse: constant-velocity + damping)
        for (int c = 0; c < 6; c++) {
            A_[0][c] = P[0][c] + dt * P[2][c];
            A_[1][c] = P[1][c] + dt * P[3][c];
            A_[2][c] = a * P[2][c];
            A_[3][c] = a * P[3][c];
            A_[4][c] = P[4][c] + dt * P[5][c];
            A_[5][c] = P[5][c];
        }
        // Pp = A * F^T + Q
        for (int r = 0; r < 6; r++) {
            Pp[r][0] = A_[r][0] + dt * A_[r][2];
            Pp[r][1] = A_[r][1] + dt * A_[r][3];
            Pp[r][2] = a * A_[r][2];
            Pp[r][3] = a * A_[r][3];
            Pp[r][4] = A_[r][4] + dt * A_[r][5];
            Pp[r][5] = A_[r][5];
        }
        for (int i = 0; i < 6; i++) Pp[i][i] += Qd[i];

        // S = H Pp H^T + R  (H picks rows/cols 0,1,4)
        float S00 = Pp[0][0] + R0, S01 = Pp[0][1], S02 = Pp[0][4];
        float S11 = Pp[1][1] + R1, S12 = Pp[1][4], S22 = Pp[4][4] + R2;
        float c00 = S11 * S22 - S12 * S12;
        float c01 = S02 * S12 - S01 * S22;
        float c02 = S01 * S12 - S02 * S11;
        float det = S00 * c00 + S01 * c01 + S02 * c02;
        float rdet = 1.f / det;
        float i00 = c00 * rdet, i01 = c01 * rdet, i02 = c02 * rdet;
        float i11 = (S00 * S22 - S02 * S02) * rdet;
        float i12 = (S01 * S02 - S00 * S12) * rdet;
        float i22 = (S00 * S11 - S01 * S01) * rdet;

        // B = Pp H^T (cols 0,1,4);  K = B * Sinv
        float Bm[6][3], K[6][3];
        for (int r = 0; r < 6; r++) { Bm[r][0] = Pp[r][0]; Bm[r][1] = Pp[r][1]; Bm[r][2] = Pp[r][4]; }
        for (int r = 0; r < 6; r++) {
            K[r][0] = Bm[r][0] * i00 + Bm[r][1] * i01 + Bm[r][2] * i02;
            K[r][1] = Bm[r][0] * i01 + Bm[r][1] * i11 + Bm[r][2] * i12;
            K[r][2] = Bm[r][0] * i02 + Bm[r][1] * i12 + Bm[r][2] * i22;
        }
        // P_new = Pp - K * B^T
        float Pn[6][6];
        for (int r = 0; r < 6; r++)
            for (int c = 0; c < 6; c++)
                Pn[r][c] = Pp[r][c] - (K[r][0] * Bm[c][0] + K[r][1] * Bm[c][1] + K[r][2] * Bm[c][2]);

        float* row = tab + (size_t)t * ROWF;
        for (int r = 0; r < 6; r++) {
            row[r * 3 + 0] = K[r][0]; row[r * 3 + 1] = K[r][1]; row[r * 3 + 2] = K[r][2];
        }
        row[18] = i00; row[19] = i01; row[20] = i02;
        row[21] = i11; row[22] = i12; row[23] = i22;
        row[24] = det; row[25] = 0.f; row[26] = 0.f; row[27] = 0.f;

        float md = 0.f, mp = 0.f;
        for (int r = 0; r < 6; r++)
            for (int c = 0; c < 6; c++) {
                md = fmaxf(md, fabsf(Pn[r][c] - P[r][c]));
                mp = fmaxf(mp, fabsf(P[r][c]));
            }
        for (int r = 0; r < 6; r++)
            for (int c = 0; c < 6; c++) P[r][c] = Pn[r][c];
        if (t >= 8 && md <= 2e-6f * mp) { stop = t; break; }
    }
    *tstop = stop;
}

__global__ void fill_kernel(char* __restrict__ ws)
{
    int t = blockIdx.x * blockDim.x + threadIdx.x;
    int stop = *(const int*)(ws + 8);
    float* tab = (float*)(ws + 16);
    if (t >= NS || t <= stop) return;
    const float4* s4 = (const float4*)(tab + (size_t)stop * ROWF);
    float4* d4 = (float4*)(tab + (size_t)t * ROWF);
    #pragma unroll
    for (int i = 0; i < 7; i++) d4[i] = s4[i];
}

__global__ __launch_bounds__(64, 1) void ekf_main(const float* __restrict__ params,
                                                  const float* __restrict__ meas,
                                                  char* __restrict__ ws)
{
    int b = blockIdx.x * blockDim.x + threadIdx.x;  // trajectory id, 0..2047
    const float dt = DTF;
    const float fric = params[0];
    const float damping = params[1];
    const float* tab = (const float*)(ws + 16);
    const float* z = meas + (size_t)b * Tn * 3;

    float z00 = z[0], z01 = z[1], z02 = z[2];
    float z10 = z[3], z11 = z[4], z12 = z[5];
    float s0 = z00, s1 = z01, s4 = z02;
    float s2 = (z10 - z00) / dt, s3 = (z11 - z01) / dt, s5 = (z12 - z02) / dt;

    double acc = 0.0;
    float zc0 = z10, zc1 = z11, zc2 = z12;  // z for step 0 (measurement index 1)

    for (int t = 0; t < NS; ++t) {
        // software-prefetch next step's measurement
        float zn0 = 0.f, zn1 = 0.f, zn2 = 0.f;
        if (t + 1 < NS) {
            const float* zp = z + (size_t)(t + 2) * 3;
            zn0 = zp[0]; zn1 = zp[1]; zn2 = zp[2];
        }
        const float4* r4 = (const float4*)(tab + (size_t)t * ROWF);
        float4 q0 = r4[0], q1 = r4[1], q2 = r4[2], q3 = r4[3], q4 = r4[4], q5 = r4[5], q6 = r4[6];

        float p0 = fmaf(s2, dt, s0);
        float p1 = fmaf(s3, dt, s1);
        float p2 = s2 - dt * (damping * s2 + fric * sgnf(s2));
        float p3 = s3 - dt * (damping * s3 + fric * sgnf(s3));
        float p4 = fmaf(s5, dt, s4);
        float p5 = s5;

        float y0 = zc0 - p0, y1 = zc1 - p1, y2 = zc2 - p4;

        s0 = p0 + q0.x * y0 + q0.y * y1 + q0.z * y2;
        s1 = p1 + q0.w * y0 + q1.x * y1 + q1.y * y2;
        s2 = p2 + q1.z * y0 + q1.w * y1 + q2.x * y2;
        s3 = p3 + q2.y * y0 + q2.z * y1 + q2.w * y2;
        s4 = p4 + q3.x * y0 + q3.y * y1 + q3.z * y2;
        s5 = p5 + q3.w * y0 + q4.x * y1 + q4.y * y2;

        float i00 = q4.z, i01 = q4.w, i02 = q5.x, i11 = q5.y, i12 = q5.z, i22 = q5.w;
        float det = q6.x;
        float u0 = i00 * y0 + i01 * y1 + i02 * y2;
        float u1 = i01 * y0 + i11 * y1 + i12 * y2;
        float u2 = i02 * y0 + i12 * y1 + i22 * y2;
        acc += (double)(det + y0 * u0 + y1 * u1 + y2 * u2);

        zc0 = zn0; zc1 = zn1; zc2 = zn2;
    }

    // wave-level reduction, then one fp64 atomic per wave
    for (int off = 32; off; off >>= 1) acc += __shfl_down(acc, off);
    if ((threadIdx.x & 63) == 0) atomicAdd((double*)ws, acc);
}

__global__ void finalize_kernel(const char* __restrict__ ws, float* __restrict__ out)
{
    if (threadIdx.x == 0 && blockIdx.x == 0) {
        double acc = *(const double*)ws;
        out[0] = (float)(acc / ((double)Bn * (double)NS));
    }
}

extern "C" void kernel_launch(void* const* d_in, const int* in_sizes, int n_in,
                              void* d_out, int out_size, void* d_ws, size_t ws_size,
                              hipStream_t stream)
{
    const float* params = (const float*)d_in[0];
    const float* meas = (const float*)d_in[1];
    char* ws = (char*)d_ws;
    float* out = (float*)d_out;

    hipLaunchKernelGGL(riccati_kernel, dim3(1), dim3(64), 0, stream, params, ws);
    hipLaunchKernelGGL(fill_kernel, dim3((NS + 255) / 256), dim3(256), 0, stream, ws);
    hipLaunchKernelGGL(ekf_main, dim3(Bn / 64), dim3(64), 0, stream, params, meas, ws);
    hipLaunchKernelGGL(finalize_kernel, dim3(1), dim3(1), 0, stream, ws, out);
}

// Round 2
// 121.093 us; speedup vs baseline: 6.9669x; 6.9669x over previous
//
#include <hip/hip_runtime.h>
#include <hip/hip_bf16.h>

#define DTF (1.0f/120.0f)

constexpr int Bn = 2048;
constexpr int Tn = 2048;
constexpr int NS = Tn - 1;          // 2047 scan steps
constexpr int RIC_CAP = 768;        // max Riccati iterations (converges in ~100)
constexpr int TAB_ROWS = RIC_CAP + 16;
constexpr int NCH = 64;             // grid.y: c==0 exact head, c=1..63 tail pieces
constexpr int WARM = 64;            // warm-up steps for tail chunks
constexpr int GX = Bn / 256;        // 8 blocks along trajectories

// ws layout (bytes):
//   8      : int stop
//   16     : converged gain row, 8 floats
//   64     : table, TAB_ROWS rows x 8 floats {kx0,kx1,kt0,kt1,isx,ist,det,pad}
//   WS_PART: GX*NCH doubles (per-block partial sums)
constexpr int WS_STOP = 8;
constexpr int WS_CONV = 16;
constexpr int WS_TAB  = 64;
constexpr int WS_PART = WS_TAB + TAB_ROWS * 8 * 4;   // 25152, 8-aligned
constexpr int NPART = GX * NCH;                       // 512

__device__ __forceinline__ float sgnf(float x) { return (float)((x > 0.f) - (x < 0.f)); }

// ---------------- Riccati: two exact 2x2 blocks (pos/vel shared by x,y; theta) ---------
__global__ void riccati_kernel(const float* __restrict__ params, char* __restrict__ ws)
{
    if (threadIdx.x != 0 || blockIdx.x != 0) return;
    const float dt = DTF;
    const float damping = params[1];
    const float a = 1.f - dt * damping;
    const float qp = 2e-10f, qv = 3e-7f, qth = 1e-2f, qdth = 1e-1f;
    const float Rp = 2.5e-7f, Rt = 9.1e-3f;
    float* tab = (float*)(ws + WS_TAB);

    float x00 = 0.01f, x01 = 0.f, x11 = 0.01f;   // pos/vel block (x == y)
    float t00 = 0.01f, t01 = 0.f, t11 = 0.01f;   // theta block
    int stop = RIC_CAP - 1;
    for (int t = 0; t < RIC_CAP; ++t) {
        // pos/vel: F=[[1,dt],[0,a]]
        float Pp00 = x00 + 2.f*dt*x01 + dt*dt*x11 + qp;
        float Pp01 = a * (x01 + dt*x11);
        float Pp11 = a*a*x11 + qv;
        float Sx = Pp00 + Rp, isx = 1.f/Sx;
        float kx0 = Pp00*isx, kx1 = Pp01*isx;
        float nx00 = Pp00 - kx0*Pp00, nx01 = Pp01 - kx0*Pp01, nx11 = Pp11 - kx1*Pp01;
        // theta: F=[[1,dt],[0,1]]
        float Tp00 = t00 + 2.f*dt*t01 + dt*dt*t11 + qth;
        float Tp01 = t01 + dt*t11;
        float Tp11 = t11 + qdth;
        float St = Tp00 + Rt, ist = 1.f/St;
        float kt0 = Tp00*ist, kt1 = Tp01*ist;
        float nt00 = Tp00 - kt0*Tp00, nt01 = Tp01 - kt0*Tp01, nt11 = Tp11 - kt1*Tp01;

        float* row = tab + (size_t)t * 8;
        row[0]=kx0; row[1]=kx1; row[2]=kt0; row[3]=kt1;
        row[4]=isx; row[5]=ist; row[6]=Sx*Sx*St; row[7]=0.f;

        float md = fmaxf(fmaxf(fabsf(nx00-x00), fabsf(nx01-x01)), fabsf(nx11-x11));
        md = fmaxf(md, fmaxf(fmaxf(fabsf(nt00-t00), fabsf(nt01-t01)), fabsf(nt11-t11)));
        float mp = fmaxf(fmaxf(fabsf(nx00), fabsf(nx11)), fmaxf(fabsf(nt00), fabsf(nt11)));
        x00=nx00; x01=nx01; x11=nx11; t00=nt00; t01=nt01; t11=nt11;
        if (t >= 32 && md <= 2e-6f * mp) { stop = t; break; }
    }
    *(int*)(ws + WS_STOP) = stop;
    float* cvv = (float*)(ws + WS_CONV);
    const float* srow = tab + (size_t)stop * 8;
    #pragma unroll
    for (int i = 0; i < 8; ++i) cvv[i] = srow[i];
}

// ---------------- helpers: static-index register loads -------------------------------
__device__ __forceinline__ void zload(float (&dst)[12], const float* __restrict__ zr, int jj)
{
    int m = min(jj, Tn - 5) * 3 + 3;   // measurements for steps jj..jj+3 (z index jj+1..jj+4)
    #pragma unroll
    for (int q = 0; q < 12; ++q) dst[q] = zr[m + q];
}
__device__ __forceinline__ void gload(float (&dst)[32], const float* __restrict__ tab, int jj)
{
    const float* g = tab + (size_t)jj * 8;  // rows jj..jj+3 (caller keeps jj < TAB_ROWS-4)
    #pragma unroll
    for (int q = 0; q < 32; ++q) dst[q] = g[q];
}

// ---------------- main filter ---------------------------------------------------------
__global__ __launch_bounds__(256, 2) void ekf_main(const float* __restrict__ params,
                                                   const float* __restrict__ meas,
                                                   char* __restrict__ ws)
{
    const int b = blockIdx.x * 256 + threadIdx.x;   // trajectory
    const int c = blockIdx.y;                       // chunk
    const float dt = DTF;
    const float fric = params[0];
    const float damping = params[1];
    const float a = 1.f - dt * damping;
    const float dfr = dt * fric;
    const int stop = *(const int*)(ws + WS_STOP);
    const float* __restrict__ cvv = (const float*)(ws + WS_CONV);
    const float ckx0=cvv[0], ckx1=cvv[1], ckt0=cvv[2], ckt1=cvv[3];
    const float cisx=cvv[4], cist=cvv[5], cdet=cvv[6];
    const float* __restrict__ tab = (const float*)(ws + WS_TAB);
    const float* __restrict__ zr = meas + (size_t)b * (Tn * 3);
    double acc = 0.0;
    float s0=0.f, s1=0.f, s2=0.f, s3=0.f, s4=0.f, s5=0.f;

#define PRED_Y(ZA, K) \
    float p0 = fmaf(dt, s2, s0), p1 = fmaf(dt, s3, s1), p4 = fmaf(dt, s5, s4); \
    float p2 = fmaf(a, s2, -dfr * sgnf(s2)); \
    float p3 = fmaf(a, s3, -dfr * sgnf(s3)); \
    float y0 = ZA[3*(K)] - p0, y1 = ZA[3*(K)+1] - p1, y2 = ZA[3*(K)+2] - p4;

#define STEPT(ZA, GA, K, J) do { \
    PRED_Y(ZA, K) \
    float kx0=GA[8*(K)], kx1=GA[8*(K)+1], kt0=GA[8*(K)+2], kt1=GA[8*(K)+3]; \
    float isx=GA[8*(K)+4], ist=GA[8*(K)+5], det=GA[8*(K)+6]; \
    s0=fmaf(kx0,y0,p0); s1=fmaf(kx0,y1,p1); \
    s2=fmaf(kx1,y0,p2); s3=fmaf(kx1,y1,p3); \
    s4=fmaf(kt0,y2,p4); s5=fmaf(kt1,y2,s5); \
    if ((J) < jend) acc += (double)(det + isx*fmaf(y0,y0,y1*y1) + ist*y2*y2); \
} while (0)

#define STEPC(ZA, K, J) do { \
    PRED_Y(ZA, K) \
    s0=fmaf(ckx0,y0,p0); s1=fmaf(ckx0,y1,p1); \
    s2=fmaf(ckx1,y0,p2); s3=fmaf(ckx1,y1,p3); \
    s4=fmaf(ckt0,y2,p4); s5=fmaf(ckt1,y2,s5); \
    if ((J) >= j0 && (J) < jend) acc += (double)(cdet + cisx*fmaf(y0,y0,y1*y1) + cist*y2*y2); \
} while (0)

    if (c == 0) {
        // exact head: steps [0, stop], reference init, table gains
        const int jend = stop + 1;
        {
            float z0=zr[0], z1=zr[1], z2=zr[2], z3=zr[3], z4=zr[4], z5=zr[5];
            s0=z0; s1=z1; s4=z2;
            s2=(z3-z0)/dt; s3=(z4-z1)/dt; s5=(z5-z2)/dt;
        }
        float zf0[12], zf1[12], gf0[32], gf1[32];
        zload(zf0, zr, 0);  gload(gf0, tab, 0);
        zload(zf1, zr, 4);  gload(gf1, tab, 4);
        for (int jb = 0; jb < jend; jb += 8) {
            STEPT(zf0, gf0, 0, jb+0); STEPT(zf0, gf0, 1, jb+1);
            STEPT(zf0, gf0, 2, jb+2); STEPT(zf0, gf0, 3, jb+3);
            zload(zf0, zr, jb+8);  gload(gf0, tab, jb+8);    // rows <= stop+12 < TAB_ROWS
            STEPT(zf1, gf1, 0, jb+4); STEPT(zf1, gf1, 1, jb+5);
            STEPT(zf1, gf1, 2, jb+6); STEPT(zf1, gf1, 3, jb+7);
            zload(zf1, zr, jb+12); gload(gf1, tab, jb+12);
        }
    } else {
        // tail piece with warm-up, converged gains only
        const int rem = NS - (stop + 1);
        const int Lr = (rem + (NCH - 2)) / (NCH - 1);
        const int j0 = stop + 1 + (c - 1) * Lr;
        const int jend = min(j0 + Lr, NS);
        if (j0 < NS) {
            const int jw = max(0, j0 - WARM);
            {
                const float* zi = zr + (size_t)jw * 3;
                float z0=zi[0], z1=zi[1], z2=zi[2], z3=zi[3], z4=zi[4], z5=zi[5];
                s0=z0; s1=z1; s4=z2;
                s2=(z3-z0)/dt; s3=(z4-z1)/dt; s5=(z5-z2)/dt;
            }
            float zf0[12], zf1[12], zf2[12], zf3[12];
            zload(zf0, zr, jw);    zload(zf1, zr, jw+4);
            zload(zf2, zr, jw+8);  zload(zf3, zr, jw+12);
            for (int jb = jw; jb < jend; jb += 16) {
                STEPC(zf0, 0, jb+0);  STEPC(zf0, 1, jb+1);
                STEPC(zf0, 2, jb+2);  STEPC(zf0, 3, jb+3);
                zload(zf0, zr, jb+16);
                STEPC(zf1, 0, jb+4);  STEPC(zf1, 1, jb+5);
                STEPC(zf1, 2, jb+6);  STEPC(zf1, 3, jb+7);
                zload(zf1, zr, jb+20);
                STEPC(zf2, 0, jb+8);  STEPC(zf2, 1, jb+9);
                STEPC(zf2, 2, jb+10); STEPC(zf2, 3, jb+11);
                zload(zf2, zr, jb+24);
                STEPC(zf3, 0, jb+12); STEPC(zf3, 1, jb+13);
                STEPC(zf3, 2, jb+14); STEPC(zf3, 3, jb+15);
                zload(zf3, zr, jb+28);
            }
        }
    }

    // per-wave shuffle reduce, per-block partial (no global atomics, deterministic order)
    for (int off = 32; off; off >>= 1) acc += __shfl_down(acc, off);
    __shared__ double wpart[4];
    if ((threadIdx.x & 63) == 0) wpart[threadIdx.x >> 6] = acc;
    __syncthreads();
    if (threadIdx.x == 0) {
        double t = wpart[0] + wpart[1] + wpart[2] + wpart[3];
        ((double*)(ws + WS_PART))[blockIdx.y * gridDim.x + blockIdx.x] = t;
    }
#undef STEPC
#undef STEPT
#undef PRED_Y
}

// ---------------- final reduction -----------------------------------------------------
__global__ void finalize_kernel(const char* __restrict__ ws, float* __restrict__ out)
{
    const double* part = (const double*)(ws + WS_PART);
    const int tid = threadIdx.x;          // 512 threads
    double v = part[tid];
    for (int off = 32; off; off >>= 1) v += __shfl_down(v, off);
    __shared__ double wp[8];
    if ((tid & 63) == 0) wp[tid >> 6] = v;
    __syncthreads();
    if (tid == 0) {
        double t = 0.0;
        #pragma unroll
        for (int i = 0; i < 8; ++i) t += wp[i];
        out[0] = (float)(t / ((double)Bn * (double)NS));
    }
}

extern "C" void kernel_launch(void* const* d_in, const int* in_sizes, int n_in,
                              void* d_out, int out_size, void* d_ws, size_t ws_size,
                              hipStream_t stream)
{
    const float* params = (const float*)d_in[0];
    const float* meas = (const float*)d_in[1];
    char* ws = (char*)d_ws;
    float* out = (float*)d_out;

    hipLaunchKernelGGL(riccati_kernel, dim3(1), dim3(64), 0, stream, params, ws);
    hipLaunchKernelGGL(ekf_main, dim3(GX, NCH), dim3(256), 0, stream, params, meas, ws);
    hipLaunchKernelGGL(finalize_kernel, dim3(1), dim3(512), 0, stream, ws, out);
}

// Round 3
// 111.337 us; speedup vs baseline: 7.5774x; 1.0876x over previous
//
#include <hip/hip_runtime.h>

#define DTF (1.0f/120.0f)

constexpr int Bn = 2048;
constexpr int Tn = 2048;
constexpr int NS = Tn - 1;          // 2047 scan steps
constexpr int RIC_CAP = 256;        // Riccati iteration cap
constexpr int TAB_ROWS = 512;       // table rows (>= any index touched + prefetch)
constexpr int NCH = 128;            // time chunks
constexpr int LCH = 16;             // steps owned per chunk (128*16 >= 2047)
constexpr int SPAN = 96;            // executed span per chunk (multiple of 24)
constexpr int GX = Bn / 256;        // 8 trajectory blocks

// ws layout (bytes)
constexpr int WS_STOP = 8;
constexpr int WS_CONV = 16;
constexpr int WS_TAB  = 64;                           // TAB_ROWS x 8 floats
constexpr int WS_PART = WS_TAB + TAB_ROWS * 8 * 4;    // per-block partials (doubles)
constexpr int NPART = GX * NCH;                        // 1024

__device__ __forceinline__ float sgnf(float x) { return (float)((x > 0.f) - (x < 0.f)); }

// ---- Riccati: two exact 2x2 blocks; thread 0 serial, then all threads fill tail ----
__global__ void riccati_kernel(const float* __restrict__ params, char* __restrict__ ws)
{
    __shared__ int s_stop;
    __shared__ float s_conv[8];
    float* tab = (float*)(ws + WS_TAB);
    if (threadIdx.x == 0) {
        const float dt = DTF;
        const float damping = params[1];
        const float a = 1.f - dt * damping;
        const float qp = 2e-10f, qv = 3e-7f, qth = 1e-2f, qdth = 1e-1f;
        const float Rp = 2.5e-7f, Rt = 9.1e-3f;
        float x00 = 0.01f, x01 = 0.f, x11 = 0.01f;   // pos/vel block (x == y)
        float t00 = 0.01f, t01 = 0.f, t11 = 0.01f;   // theta block
        int stop = RIC_CAP - 1;
        for (int t = 0; t < RIC_CAP; ++t) {
            float Pp00 = x00 + 2.f*dt*x01 + dt*dt*x11 + qp;
            float Pp01 = a * (x01 + dt*x11);
            float Pp11 = a*a*x11 + qv;
            float Sx = Pp00 + Rp, isx = 1.f/Sx;
            float kx0 = Pp00*isx, kx1 = Pp01*isx;
            float nx00 = Pp00 - kx0*Pp00, nx01 = Pp01 - kx0*Pp01, nx11 = Pp11 - kx1*Pp01;
            float Tp00 = t00 + 2.f*dt*t01 + dt*dt*t11 + qth;
            float Tp01 = t01 + dt*t11;
            float Tp11 = t11 + qdth;
            float St = Tp00 + Rt, ist = 1.f/St;
            float kt0 = Tp00*ist, kt1 = Tp01*ist;
            float nt00 = Tp00 - kt0*Tp00, nt01 = Tp01 - kt0*Tp01, nt11 = Tp11 - kt1*Tp01;
            float* row = tab + (size_t)t * 8;
            row[0]=kx0; row[1]=kx1; row[2]=kt0; row[3]=kt1;
            row[4]=isx; row[5]=ist; row[6]=Sx*Sx*St; row[7]=0.f;
            float md = fmaxf(fmaxf(fabsf(nx00-x00), fabsf(nx01-x01)), fabsf(nx11-x11));
            md = fmaxf(md, fmaxf(fmaxf(fabsf(nt00-t00), fabsf(nt01-t01)), fabsf(nt11-t11)));
            float mp = fmaxf(fmaxf(fabsf(nx00), fabsf(nx11)), fmaxf(fabsf(nt00), fabsf(nt11)));
            x00=nx00; x01=nx01; x11=nx11; t00=nt00; t01=nt01; t11=nt11;
            if (t >= 48 && md <= 1e-5f * mp) { stop = t; break; }
        }
        *(int*)(ws + WS_STOP) = stop;
        float* cv = (float*)(ws + WS_CONV);
        const float* srow = tab + (size_t)stop * 8;
        #pragma unroll
        for (int i = 0; i < 8; ++i) { cv[i] = srow[i]; s_conv[i] = srow[i]; }
        s_stop = stop;
    }
    __syncthreads();
    const int stop = s_stop;
    const float c0=s_conv[0], c1=s_conv[1], c2=s_conv[2], c3=s_conv[3];
    const float c4=s_conv[4], c5=s_conv[5], c6=s_conv[6];
    for (int r = stop + 1 + threadIdx.x; r < TAB_ROWS; r += blockDim.x) {
        float* row = tab + (size_t)r * 8;
        row[0]=c0; row[1]=c1; row[2]=c2; row[3]=c3; row[4]=c4; row[5]=c5; row[6]=c6; row[7]=0.f;
    }
}

// ---- static-index register loads ----
__device__ __forceinline__ void zload(float (&dst)[12], const float* __restrict__ zr, int jj)
{
    int m = min(jj, Tn - 5) * 3 + 3;   // z for steps jj..jj+3 (meas idx jj+1..jj+4)
    #pragma unroll
    for (int q = 0; q < 12; ++q) dst[q] = zr[m + q];
}
__device__ __forceinline__ void gload(float (&dst)[32], const float* __restrict__ tab, int jj)
{
    const float* g = tab + (size_t)min(jj, TAB_ROWS - 4) * 8;
    #pragma unroll
    for (int q = 0; q < 32; ++q) dst[q] = g[q];
}

// ---- main filter: uniform time chunks, warm-up start, no straggler ----
__global__ __launch_bounds__(256, 4) void ekf_main(const float* __restrict__ params,
                                                   const float* __restrict__ meas,
                                                   char* __restrict__ ws)
{
    const int b = blockIdx.x * 256 + threadIdx.x;   // trajectory
    const int c = blockIdx.y;                       // time chunk
    const float dt = DTF;
    const float fric = params[0];
    const float damping = params[1];
    const float a = 1.f - dt * damping;
    const float dfr = dt * fric;
    const int stop = *(const int*)(ws + WS_STOP);
    const float* __restrict__ cvv = (const float*)(ws + WS_CONV);
    const float ckx0=cvv[0], ckx1=cvv[1], ckt0=cvv[2], ckt1=cvv[3];
    const float cisx=cvv[4], cist=cvv[5], cdet=cvv[6];
    const float* __restrict__ tab = (const float*)(ws + WS_TAB);
    const float* __restrict__ zr = meas + (size_t)b * (Tn * 3);

    const int j0   = c * LCH;
    const int jend = min(j0 + LCH, NS);
    const int jw   = max(0, jend - SPAN);   // extended warm-up fills execution quantum

    double acc = 0.0;
    float s0, s1, s2, s3, s4, s5;
    {
        const float* zi = zr + (size_t)jw * 3;
        float z0=zi[0], z1=zi[1], z2=zi[2], z3=zi[3], z4=zi[4], z5=zi[5];
        s0=z0; s1=z1; s4=z2;
        s2=(z3-z0)/dt; s3=(z4-z1)/dt; s5=(z5-z2)/dt;
    }

#define PRED_Y(ZA, K) \
    float p0 = fmaf(dt, s2, s0), p1 = fmaf(dt, s3, s1), p4 = fmaf(dt, s5, s4); \
    float p2 = fmaf(a, s2, -dfr * sgnf(s2)); \
    float p3 = fmaf(a, s3, -dfr * sgnf(s3)); \
    float y0 = ZA[3*(K)] - p0, y1 = ZA[3*(K)+1] - p1, y2 = ZA[3*(K)+2] - p4;

#define STEPC(ZA, K, J) do { \
    PRED_Y(ZA, K) \
    s0=fmaf(ckx0,y0,p0); s1=fmaf(ckx0,y1,p1); \
    s2=fmaf(ckx1,y0,p2); s3=fmaf(ckx1,y1,p3); \
    s4=fmaf(ckt0,y2,p4); s5=fmaf(ckt1,y2,s5); \
    if ((J) >= j0 && (J) < jend) acc += (double)(cdet + cisx*fmaf(y0,y0,y1*y1) + cist*y2*y2); \
} while (0)

#define STEPT(ZA, GA, K, J) do { \
    PRED_Y(ZA, K) \
    float kx0=GA[8*(K)], kx1=GA[8*(K)+1], kt0=GA[8*(K)+2], kt1=GA[8*(K)+3]; \
    float isx=GA[8*(K)+4], ist=GA[8*(K)+5], det=GA[8*(K)+6]; \
    s0=fmaf(kx0,y0,p0); s1=fmaf(kx0,y1,p1); \
    s2=fmaf(kx1,y0,p2); s3=fmaf(kx1,y1,p3); \
    s4=fmaf(kt0,y2,p4); s5=fmaf(kt1,y2,s5); \
    if ((J) >= j0 && (J) < jend) acc += (double)(det + isx*fmaf(y0,y0,y1*y1) + ist*y2*y2); \
} while (0)

#define GROUPC(ZA, J) do { STEPC(ZA,0,(J)); STEPC(ZA,1,(J)+1); STEPC(ZA,2,(J)+2); STEPC(ZA,3,(J)+3); } while (0)

    if (jw > stop) {
        // converged-gain path: 24-step loop, 6-batch z FIFO (24-step load lead),
        // sched_barrier pins each batch's loads so the compiler can't sink them.
        float zA[12], zB[12], zC[12], zD[12], zE[12], zF[12];
        zload(zA, zr, jw);      zload(zB, zr, jw + 4);
        zload(zC, zr, jw + 8);  zload(zD, zr, jw + 12);
        zload(zE, zr, jw + 16); zload(zF, zr, jw + 20);
        for (int jb = jw; jb < jend; jb += 24) {
            GROUPC(zA, jb+0);  zload(zA, zr, jb+24); __builtin_amdgcn_sched_barrier(0);
            GROUPC(zB, jb+4);  zload(zB, zr, jb+28); __builtin_amdgcn_sched_barrier(0);
            GROUPC(zC, jb+8);  zload(zC, zr, jb+32); __builtin_amdgcn_sched_barrier(0);
            GROUPC(zD, jb+12); zload(zD, zr, jb+36); __builtin_amdgcn_sched_barrier(0);
            GROUPC(zE, jb+16); zload(zE, zr, jb+40); __builtin_amdgcn_sched_barrier(0);
            GROUPC(zF, jb+20); zload(zF, zr, jb+44); __builtin_amdgcn_sched_barrier(0);
        }
    } else {
        // table path (chunks overlapping the transient head; gains wave-uniform -> s_loads)
        float zf0[12], zf1[12], gf0[32], gf1[32];
        zload(zf0, zr, jw);     gload(gf0, tab, jw);
        zload(zf1, zr, jw + 4); gload(gf1, tab, jw + 4);
        for (int jb = jw; jb < jend; jb += 8) {
            STEPT(zf0, gf0, 0, jb+0); STEPT(zf0, gf0, 1, jb+1);
            STEPT(zf0, gf0, 2, jb+2); STEPT(zf0, gf0, 3, jb+3);
            zload(zf0, zr, jb+8);  gload(gf0, tab, jb+8);
            __builtin_amdgcn_sched_barrier(0);
            STEPT(zf1, gf1, 0, jb+4); STEPT(zf1, gf1, 1, jb+5);
            STEPT(zf1, gf1, 2, jb+6); STEPT(zf1, gf1, 3, jb+7);
            zload(zf1, zr, jb+12); gload(gf1, tab, jb+12);
            __builtin_amdgcn_sched_barrier(0);
        }
    }

#undef GROUPC
#undef STEPT
#undef STEPC
#undef PRED_Y

    // per-wave shuffle reduce -> per-block partial (deterministic, no atomics)
    for (int off = 32; off; off >>= 1) acc += __shfl_down(acc, off);
    __shared__ double wpart[4];
    if ((threadIdx.x & 63) == 0) wpart[threadIdx.x >> 6] = acc;
    __syncthreads();
    if (threadIdx.x == 0) {
        double t = wpart[0] + wpart[1] + wpart[2] + wpart[3];
        ((double*)(ws + WS_PART))[blockIdx.y * gridDim.x + blockIdx.x] = t;
    }
}

// ---- final reduction over 1024 partials ----
__global__ void finalize_kernel(const char* __restrict__ ws, float* __restrict__ out)
{
    const double* part = (const double*)(ws + WS_PART);
    const int tid = threadIdx.x;          // 1024 threads
    double v = part[tid];
    for (int off = 32; off; off >>= 1) v += __shfl_down(v, off);
    __shared__ double wp[16];
    if ((tid & 63) == 0) wp[tid >> 6] = v;
    __syncthreads();
    if (tid == 0) {
        double t = 0.0;
        #pragma unroll
        for (int i = 0; i < 16; ++i) t += wp[i];
        out[0] = (float)(t / ((double)Bn * (double)NS));
    }
}

extern "C" void kernel_launch(void* const* d_in, const int* in_sizes, int n_in,
                              void* d_out, int out_size, void* d_ws, size_t ws_size,
                              hipStream_t stream)
{
    const float* params = (const float*)d_in[0];
    const float* meas = (const float*)d_in[1];
    char* ws = (char*)d_ws;
    float* out = (float*)d_out;

    hipLaunchKernelGGL(riccati_kernel, dim3(1), dim3(256), 0, stream, params, ws);
    hipLaunchKernelGGL(ekf_main, dim3(GX, NCH), dim3(256), 0, stream, params, meas, ws);
    hipLaunchKernelGGL(finalize_kernel, dim3(1), dim3(1024), 0, stream, ws, out);
}

// Round 4
// 68.025 us; speedup vs baseline: 12.4019x; 1.6367x over previous
//
#include <hip/hip_runtime.h>

#define DTF (1.0f/120.0f)

constexpr int Bn = 2048;
constexpr int Tn = 2048;
constexpr int NS = Tn - 1;          // 2047 scan steps
constexpr int RIC_CAP = 256;        // Riccati iteration cap
constexpr int TAB_ROWS = 512;       // gain-table rows (riccati fills tail with converged row)
constexpr int NCH = 64;             // time chunks
constexpr int LCH = 32;             // owned steps per chunk (64*32 >= 2047)
constexpr int SPAN = 72;            // executed span per chunk (warm-up ~40)
constexpr int GX = Bn / 256;        // 8 trajectory blocks

// ws layout (bytes)
constexpr int WS_STOP = 8;
constexpr int WS_CONV = 16;
constexpr int WS_TAB  = 64;                           // TAB_ROWS x 8 floats
constexpr int WS_PART = WS_TAB + TAB_ROWS * 8 * 4;    // per-block partials (doubles)
constexpr int NPART = GX * NCH;                        // 512

// ---- Riccati: two exact 2x2 blocks; thread 0 serial, all threads fill tail ----
__global__ void riccati_kernel(const float* __restrict__ params, char* __restrict__ ws)
{
    __shared__ int s_stop;
    __shared__ float s_conv[8];
    float* tab = (float*)(ws + WS_TAB);
    if (threadIdx.x == 0) {
        const float dt = DTF;
        const float damping = params[1];
        const float a = 1.f - dt * damping;
        const float qp = 2e-10f, qv = 3e-7f, qth = 1e-2f, qdth = 1e-1f;
        const float Rp = 2.5e-7f, Rt = 9.1e-3f;
        float x00 = 0.01f, x01 = 0.f, x11 = 0.01f;   // pos/vel block (x == y)
        float t00 = 0.01f, t01 = 0.f, t11 = 0.01f;   // theta block
        int stop = RIC_CAP - 1;
        for (int t = 0; t < RIC_CAP; ++t) {
            float Pp00 = x00 + 2.f*dt*x01 + dt*dt*x11 + qp;
            float Pp01 = a * (x01 + dt*x11);
            float Pp11 = a*a*x11 + qv;
            float Sx = Pp00 + Rp, isx = __builtin_amdgcn_rcpf(Sx);
            float kx0 = Pp00*isx, kx1 = Pp01*isx;
            float nx00 = Pp00 - kx0*Pp00, nx01 = Pp01 - kx0*Pp01, nx11 = Pp11 - kx1*Pp01;
            float Tp00 = t00 + 2.f*dt*t01 + dt*dt*t11 + qth;
            float Tp01 = t01 + dt*t11;
            float Tp11 = t11 + qdth;
            float St = Tp00 + Rt, ist = __builtin_amdgcn_rcpf(St);
            float kt0 = Tp00*ist, kt1 = Tp01*ist;
            float nt00 = Tp00 - kt0*Tp00, nt01 = Tp01 - kt0*Tp01, nt11 = Tp11 - kt1*Tp01;
            float* row = tab + (size_t)t * 8;
            row[0]=kx0; row[1]=kx1; row[2]=kt0; row[3]=kt1;
            row[4]=isx; row[5]=ist; row[6]=Sx*Sx*St; row[7]=0.f;
            float md = fmaxf(fmaxf(fabsf(nx00-x00), fabsf(nx01-x01)), fabsf(nx11-x11));
            md = fmaxf(md, fmaxf(fmaxf(fabsf(nt00-t00), fabsf(nt01-t01)), fabsf(nt11-t11)));
            float mp = fmaxf(fmaxf(fabsf(nx00), fabsf(nx11)), fmaxf(fabsf(nt00), fabsf(nt11)));
            x00=nx00; x01=nx01; x11=nx11; t00=nt00; t01=nt01; t11=nt11;
            if (t >= 48 && md <= 1e-5f * mp) { stop = t; break; }
        }
        *(int*)(ws + WS_STOP) = stop;
        float* cv = (float*)(ws + WS_CONV);
        const float* srow = tab + (size_t)stop * 8;
        #pragma unroll
        for (int i = 0; i < 8; ++i) { cv[i] = srow[i]; s_conv[i] = srow[i]; }
        s_stop = stop;
    }
    __syncthreads();
    const int stop = s_stop;
    const float c0=s_conv[0], c1=s_conv[1], c2=s_conv[2], c3=s_conv[3];
    const float c4=s_conv[4], c5=s_conv[5], c6=s_conv[6];
    for (int r = stop + 1 + threadIdx.x; r < TAB_ROWS; r += blockDim.x) {
        float* row = tab + (size_t)r * 8;
        row[0]=c0; row[1]=c1; row[2]=c2; row[3]=c3; row[4]=c4; row[5]=c5; row[6]=c6; row[7]=0.f;
    }
}

// ---- 12-float z window for 4 steps; all-constant indices -> registers ----
struct Z12 { float w[12]; };

// vector load: requires jj % 4 == 3 so (jj*3+3)*4B is 16B-aligned.
// window floats [jj*3+3, jj*3+15) = z components for steps jj..jj+3.
__device__ __forceinline__ void zload4(Z12& s, const float* __restrict__ zr, int jj)
{
    int fs = min(jj * 3 + 3, Tn * 3 - 12);   // clamp keeps last row in-bounds (6132, %4==0)
    const float4* p = (const float4*)(zr + fs);
    float4 a = p[0], b = p[1], c = p[2];
    s.w[0]=a.x; s.w[1]=a.y; s.w[2]=a.z;  s.w[3]=a.w;
    s.w[4]=b.x; s.w[5]=b.y; s.w[6]=b.z;  s.w[7]=b.w;
    s.w[8]=c.x; s.w[9]=c.y; s.w[10]=c.z; s.w[11]=c.w;
}
// scalar fallback (head/table path, any jj)
__device__ __forceinline__ void zload1(Z12& s, const float* __restrict__ zr, int jj)
{
    int m = min(jj, Tn - 5) * 3 + 3;
    #pragma unroll
    for (int q = 0; q < 12; ++q) s.w[q] = zr[m + q];
}
__device__ __forceinline__ void gload(float (&dst)[32], const float* __restrict__ tab, int jj)
{
    const float* g = tab + (size_t)min(jj, TAB_ROWS - 4) * 8;
    #pragma unroll
    for (int q = 0; q < 32; ++q) dst[q] = g[q];
}

// ---- main filter: uniform time chunks, warm-up start, vectorized z FIFO ----
__global__ __launch_bounds__(256, 2) void ekf_main(const float* __restrict__ params,
                                                   const float* __restrict__ meas,
                                                   char* __restrict__ ws)
{
    const int b = blockIdx.x * 256 + threadIdx.x;   // trajectory
    const int c = blockIdx.y;                       // time chunk
    const float dt = DTF;
    const float fric = params[0];
    const float damping = params[1];
    const float a = 1.f - dt * damping;
    const float dfr = dt * fric;
    const int stop = *(const int*)(ws + WS_STOP);
    const float* __restrict__ cvv = (const float*)(ws + WS_CONV);
    const float ckx0=cvv[0], ckx1=cvv[1], ckt0=cvv[2], ckt1=cvv[3];
    const float cisx=cvv[4], cist=cvv[5], cdet=cvv[6];
    const float* __restrict__ tab = (const float*)(ws + WS_TAB);
    const float* __restrict__ zr = meas + (size_t)b * (Tn * 3);

    const int j0   = c * LCH;
    const int jend = min(j0 + LCH, NS);
    const int jwr  = jend - SPAN;

    double acc = 0.0;
    float s0, s1, s2, s3, s4, s5;

#define PRED_Y(ZA, K) \
    float p0 = fmaf(dt, s2, s0), p1 = fmaf(dt, s3, s1), p4 = fmaf(dt, s5, s4); \
    float p2 = fmaf(a, s2, -copysignf(dfr, s2)); \
    float p3 = fmaf(a, s3, -copysignf(dfr, s3)); \
    float y0 = (ZA).w[3*(K)] - p0, y1 = (ZA).w[3*(K)+1] - p1, y2 = (ZA).w[3*(K)+2] - p4;

#define STEPC(ZA, K, J) do { \
    PRED_Y(ZA, K) \
    s0=fmaf(ckx0,y0,p0); s1=fmaf(ckx0,y1,p1); \
    s2=fmaf(ckx1,y0,p2); s3=fmaf(ckx1,y1,p3); \
    s4=fmaf(ckt0,y2,p4); s5=fmaf(ckt1,y2,s5); \
    if ((J) >= j0 && (J) < jend) acc += (double)(cdet + cisx*fmaf(y0,y0,y1*y1) + cist*y2*y2); \
} while (0)

#define STEPT(ZA, GA, K, J) do { \
    PRED_Y(ZA, K) \
    float kx0=GA[8*(K)], kx1=GA[8*(K)+1], kt0=GA[8*(K)+2], kt1=GA[8*(K)+3]; \
    float isx=GA[8*(K)+4], ist=GA[8*(K)+5], det=GA[8*(K)+6]; \
    s0=fmaf(kx0,y0,p0); s1=fmaf(kx0,y1,p1); \
    s2=fmaf(kx1,y0,p2); s3=fmaf(kx1,y1,p3); \
    s4=fmaf(kt0,y2,p4); s5=fmaf(kt1,y2,s5); \
    if ((J) >= j0 && (J) < jend) acc += (double)(det + isx*fmaf(y0,y0,y1*y1) + ist*y2*y2); \
} while (0)

#define GROUPC(ZA, J) do { STEPC(ZA,0,(J)); STEPC(ZA,1,(J)+1); STEPC(ZA,2,(J)+2); STEPC(ZA,3,(J)+3); } while (0)

    // aligned warm start for the vector path (jw % 4 == 3); valid only if jwr >= 3
    const int jw_al = (jwr >= 3) ? (jwr - ((jwr - 3) & 3)) : 0;

    if (jwr >= 3 && jw_al > stop) {
        // converged-gain path: 24-step loop, 6-slot x4-step z FIFO via dwordx4 loads
        const int jw = jw_al;
        {
            const float* zi = zr + (size_t)jw * 3;
            float z0=zi[0], z1=zi[1], z2=zi[2], z3=zi[3], z4=zi[4], z5=zi[5];
            s0=z0; s1=z1; s4=z2;
            s2=(z3-z0)/dt; s3=(z4-z1)/dt; s5=(z5-z2)/dt;
        }
        Z12 zA, zB, zC, zD, zE, zF;
        zload4(zA, zr, jw);      zload4(zB, zr, jw + 4);
        zload4(zC, zr, jw + 8);  zload4(zD, zr, jw + 12);
        zload4(zE, zr, jw + 16); zload4(zF, zr, jw + 20);
        for (int jb = jw; jb < jend; jb += 24) {
            GROUPC(zA, jb+0);  zload4(zA, zr, jb+24); __builtin_amdgcn_sched_barrier(0);
            GROUPC(zB, jb+4);  zload4(zB, zr, jb+28); __builtin_amdgcn_sched_barrier(0);
            GROUPC(zC, jb+8);  zload4(zC, zr, jb+32); __builtin_amdgcn_sched_barrier(0);
            GROUPC(zD, jb+12); zload4(zD, zr, jb+36); __builtin_amdgcn_sched_barrier(0);
            GROUPC(zE, jb+16); zload4(zE, zr, jb+40); __builtin_amdgcn_sched_barrier(0);
            GROUPC(zF, jb+20); zload4(zF, zr, jb+44); __builtin_amdgcn_sched_barrier(0);
        }
    } else {
        // head/table path: time-correct gains, scalar loads (few blocks, span bounded)
        const int jw = max(0, jwr);
        {
            const float* zi = zr + (size_t)jw * 3;
            float z0=zi[0], z1=zi[1], z2=zi[2], z3=zi[3], z4=zi[4], z5=zi[5];
            s0=z0; s1=z1; s4=z2;
            s2=(z3-z0)/dt; s3=(z4-z1)/dt; s5=(z5-z2)/dt;
        }
        Z12 zf0, zf1;
        float gf0[32], gf1[32];
        zload1(zf0, zr, jw);     gload(gf0, tab, jw);
        zload1(zf1, zr, jw + 4); gload(gf1, tab, jw + 4);
        for (int jb = jw; jb < jend; jb += 8) {
            STEPT(zf0, gf0, 0, jb+0); STEPT(zf0, gf0, 1, jb+1);
            STEPT(zf0, gf0, 2, jb+2); STEPT(zf0, gf0, 3, jb+3);
            zload1(zf0, zr, jb+8);  gload(gf0, tab, jb+8);
            __builtin_amdgcn_sched_barrier(0);
            STEPT(zf1, gf1, 0, jb+4); STEPT(zf1, gf1, 1, jb+5);
            STEPT(zf1, gf1, 2, jb+6); STEPT(zf1, gf1, 3, jb+7);
            zload1(zf1, zr, jb+12); gload(gf1, tab, jb+12);
            __builtin_amdgcn_sched_barrier(0);
        }
    }

#undef GROUPC
#undef STEPT
#undef STEPC
#undef PRED_Y

    // per-wave shuffle reduce -> per-block partial (deterministic, no atomics)
    for (int off = 32; off; off >>= 1) acc += __shfl_down(acc, off);
    __shared__ double wpart[4];
    if ((threadIdx.x & 63) == 0) wpart[threadIdx.x >> 6] = acc;
    __syncthreads();
    if (threadIdx.x == 0) {
        double t = wpart[0] + wpart[1] + wpart[2] + wpart[3];
        ((double*)(ws + WS_PART))[blockIdx.y * gridDim.x + blockIdx.x] = t;
    }
}

// ---- final reduction over 512 partials ----
__global__ void finalize_kernel(const char* __restrict__ ws, float* __restrict__ out)
{
    const double* part = (const double*)(ws + WS_PART);
    const int tid = threadIdx.x;          // 512 threads
    double v = part[tid];
    for (int off = 32; off; off >>= 1) v += __shfl_down(v, off);
    __shared__ double wp[8];
    if ((tid & 63) == 0) wp[tid >> 6] = v;
    __syncthreads();
    if (tid == 0) {
        double t = 0.0;
        #pragma unroll
        for (int i = 0; i < 8; ++i) t += wp[i];
        out[0] = (float)(t / ((double)Bn * (double)NS));
    }
}

extern "C" void kernel_launch(void* const* d_in, const int* in_sizes, int n_in,
                              void* d_out, int out_size, void* d_ws, size_t ws_size,
                              hipStream_t stream)
{
    const float* params = (const float*)d_in[0];
    const float* meas = (const float*)d_in[1];
    char* ws = (char*)d_ws;
    float* out = (float*)d_out;

    hipLaunchKernelGGL(riccati_kernel, dim3(1), dim3(256), 0, stream, params, ws);
    hipLaunchKernelGGL(ekf_main, dim3(GX, NCH), dim3(256), 0, stream, params, meas, ws);
    hipLaunchKernelGGL(finalize_kernel, dim3(1), dim3(512), 0, stream, ws, out);
}